// Round 11
// baseline (179.225 us; speedup 1.0000x reference)
//
#include <hip/hip_runtime.h>

// VectorQuantizer: x (32,64,64,64) f32, codebook (1024,64) f32
// out = concat( quantized (32,64,64,64) f32 , indices (32,64,64) as f32 )
//
// R16 = R15's main (byte-identical compute) with PREP FUSED IN; 2 kernels.
//  - R15 post-mortem: 7th structural null; main pinned 66-68us / MfmaUtil 30.
//    Totals R10/R14/R15 = 156.4/155.4/155.5 while main varied 64-68 =>
//    ~88us non-main component (prep+rescan+gaps or harness floor) dominates.
//    This round attacks overhead, not main.
//  - prep merged into vq_main via block specialization + device flag:
//    grid 512 = guaranteed co-resident (launch_bounds(256,2) => >=2 blk/CU
//    x 256 CU; LDS 38.9KB => <=4/CU) -> spin is deadlock-free, single-kernel
//    (rocprof-replay safe). Blocks 0..131 run verbatim prep slices, then
//    __threadfence (L2 writeback, cross-XCD) + atomicAdd(flag). Everyone
//    builds A-fragments from x FIRST (prep hides under x reads), spins on
//    device-scope atomic, then runs the unchanged R15 ring.
//  - flag zeroed per-iteration by 4B hipMemsetAsync (stream-async, legal).
//    Replay with stale flag: stream data is deterministic -> benign.
//  - rescan grid 1024 -> 256.
//  - numerics bit-identical (q-unit int keys, EPS_Q 24, exact-f32 rescan).

typedef _Float16 f16x8 __attribute__((ext_vector_type(8)));
typedef float    f32x4 __attribute__((ext_vector_type(4)));

#define VQ_D    64
#define VQ_HW   4096
#define VQ_NPOS 131072
#define SC      2048.0f
#define EPS_Q   24         // flag margin in q-units (24/2048 = 1.17e-2)
// ws float offsets (stream = 32 chunks * 8192B = 256KB = 65536 floats)
#define WS_CBN  65536      // f32 cn[1024] raw (rescan)
#define WS_CNQ  66560      // f32 cn_q[1024] = 2048*cn (main C-init)
#define WS_CBT  67584      // float4 cbT4[16384] (256 KB)
#define WS_CNT  133120     // int rescan counter
#define WS_LIST 133124     // int list[131072]
#define WS_FLAG 264196     // int prep-done counter (memset to 0 per launch)

// ---------- main (prep fused) ----------
#define GLOAD_LDS(GP, LP)                                                     \
    __builtin_amdgcn_global_load_lds(                                         \
        (const __attribute__((address_space(1))) unsigned int*)(GP),          \
        (__attribute__((address_space(3))) unsigned int*)(LP), 16, 0, 0)

// stage 8KB chunk CK into ring slot byte-offset BOFF: 2 gloads per wave
#define STAGE2(CK, BOFF)                                                      \
    {                                                                         \
        const char* gs_ = (const char*)ws + (size_t)(CK) * 8192               \
                          + wv * 2048 + lane * 16;                            \
        char* ld_ = (char*)bbuf + (BOFF) + wv * 2048;                         \
        GLOAD_LDS(gs_, ld_);                                                  \
        GLOAD_LDS(gs_ + 1024, ld_ + 1024);                                    \
    }

// one 16-code tile, 4 M-tiles: 8 independent depth-3 chains (pa/pb per tile),
// 24 MFMAs; then 1 add + int-key update per output (16 outputs).
#define CT_BODY(BOFF, CI, CTG)                                                \
    {                                                                         \
        const f16x8 B0 = *(const f16x8*)(lp + (BOFF) + (CI) * 4096);          \
        const f16x8 B1 = *(const f16x8*)(lp + (BOFF) + (CI) * 4096 + 1024);   \
        const f16x8 R0 = *(const f16x8*)(lp + (BOFF) + (CI) * 4096 + 2048);   \
        const f16x8 R1 = *(const f16x8*)(lp + (BOFF) + (CI) * 4096 + 3072);   \
        const float cvq = cnq_lds[(CTG) * 16 + m];                            \
        const f32x4 Ci = {cvq, cvq, cvq, cvq};                                \
        f32x4 pa[4], pb[4];                                                   \
        __builtin_amdgcn_s_setprio(1);                                        \
        _Pragma("unroll")                                                     \
        for (int tl = 0; tl < 4; ++tl) {                                      \
            pa[tl] = __builtin_amdgcn_mfma_f32_16x16x32_f16(Ak[tl][0], B0, Ci,    0,0,0); \
            pb[tl] = __builtin_amdgcn_mfma_f32_16x16x32_f16(Ak[tl][1], B1, zero4, 0,0,0); \
        }                                                                     \
        _Pragma("unroll")                                                     \
        for (int tl = 0; tl < 4; ++tl) {                                      \
            pa[tl] = __builtin_amdgcn_mfma_f32_16x16x32_f16(Ah[tl][0], R0, pa[tl], 0,0,0); \
            pb[tl] = __builtin_amdgcn_mfma_f32_16x16x32_f16(Ah[tl][1], R1, pb[tl], 0,0,0); \
        }                                                                     \
        _Pragma("unroll")                                                     \
        for (int tl = 0; tl < 4; ++tl) {                                      \
            pa[tl] = __builtin_amdgcn_mfma_f32_16x16x32_f16(Ra[tl][0], B0, pa[tl], 0,0,0); \
            pb[tl] = __builtin_amdgcn_mfma_f32_16x16x32_f16(Ra[tl][1], B1, pb[tl], 0,0,0); \
        }                                                                     \
        __builtin_amdgcn_s_setprio(0);                                        \
        const int cbase_ = (CTG) * 16 + m;                                    \
        _Pragma("unroll")                                                     \
        for (int tl = 0; tl < 4; ++tl)                                        \
            _Pragma("unroll")                                                 \
            for (int r = 0; r < 4; ++r) {                                     \
                const float q_ = pa[tl][r] + pb[tl][r];                       \
                const int k_ = ((int)q_ << 10) | cbase_;                      \
                int md_;                                                      \
                asm("v_med3_i32 %0, %1, %2, %3"                               \
                    : "=v"(md_) : "v"(k_), "v"(d1[tl][r]), "v"(d2[tl][r]));   \
                d2[tl][r] = md_;                                              \
                d1[tl][r] = (k_ < d1[tl][r]) ? k_ : d1[tl][r];                \
            }                                                                 \
    }

// ring iteration: wait own chunk-T loads (counted), sync, prefetch T+3,
// compute chunk T (2 ct). VMSTR is the counted vmcnt literal.
#define ITER_T(VMSTR, DOSTAGE, T)                                             \
    {                                                                         \
        asm volatile("s_waitcnt " VMSTR ::: "memory");                        \
        __builtin_amdgcn_s_barrier();                                         \
        if (DOSTAGE) STAGE2((T) + 3, (((T) + 3) & 3) * 8192)                  \
        const int base_ = ((T) & 3) * 8192;                                   \
        CT_BODY(base_, 0, (T) * 2)                                            \
        CT_BODY(base_, 1, (T) * 2 + 1)                                        \
    }

__global__ __launch_bounds__(256, 2)
void vq_main(const float* __restrict__ x,
             const float* __restrict__ cb,
             float* __restrict__ ws,
             float* __restrict__ out,
             float* __restrict__ idx_out)
{
    __shared__ f16x8 bbuf[4 * 512];   // 4-slot ring, 8KB (2 ct) per slot
    __shared__ float cnq_lds[1024];   // 2048*||e||^2
    __shared__ int   sk[256];
    __shared__ int   smg[256];

    const int tid  = threadIdx.x;
    const int lane = tid & 63;
    const int wv   = tid >> 6;        // 4 waves, 64 positions each
    const int m    = lane & 15;
    const int q    = lane >> 4;
    const int bid  = blockIdx.x;

    // ================= fused prep (blocks 0..131), verbatim R15 =================
    if (bid < 64) {
        const int it   = bid * 256 + tid;            // [0, 16384)
        const int ct   = it >> 8;
        const int s    = (it >> 6) & 3;
        const int ln   = it & 63;
        const int ks   = s & 1, isR = s >> 1;
        const int n    = ct * 16 + (ln & 15);        // code (B column)
        const int k0   = ks * 32 + (ln >> 4) * 8;    // dim  (B row)
        const float* src = cb + n * 64 + k0;
        f16x8 o;
        #pragma unroll
        for (int j = 0; j < 8; ++j) {
            const float bv = src[j];
            const _Float16 bh = (_Float16)bv;
            o[j] = isR ? (_Float16)((bv - (float)bh) * (-2.0f * SC))
                       : (_Float16)(-2.0f * (float)bh);
        }
        ((f16x8*)ws)[it] = o;
    } else if (bid < 128) {
        const int it = (bid - 64) * 256 + tid;       // [0, 16384)
        const int k = it >> 4, j4 = it & 15;
        ((float4*)(ws + WS_CBT))[j4 * 1024 + k] = ((const float4*)cb)[it];
    } else if (bid < 132) {
        const int k = (bid - 128) * 256 + tid;       // [0, 1024)
        const float4* row = (const float4*)(cb + k * 64);
        float a0 = 0.f, a1 = 0.f, a2 = 0.f, a3 = 0.f;
        #pragma unroll
        for (int j = 0; j < 16; ++j) {
            const float4 c = row[j];
            a0 = fmaf(c.x, c.x, a0); a1 = fmaf(c.y, c.y, a1);
            a2 = fmaf(c.z, c.z, a2); a3 = fmaf(c.w, c.w, a3);
        }
        const float cn = (a0 + a1) + (a2 + a3);
        ws[WS_CBN + k] = cn;                         // raw (rescan)
        ws[WS_CNQ + k] = cn * 2048.0f;               // q-units (main)
        if (k == 0) ((int*)ws)[WS_CNT] = 0;
    }
    if (bid < 132) {
        __syncthreads();                             // slice stores executed
        if (tid == 0) {
            __threadfence();                         // L2 writeback: device-visible
            atomicAdd((int*)ws + WS_FLAG, 1);
        }
    }

    // ---- A fragments from x (independent of ws; hides prep latency) ----
    const int p0 = bid * 256;         // block: 256 consecutive positions
    const int b  = p0 >> 12;
    const int n0 = p0 & (VQ_HW - 1);
    const float* xw = x + (size_t)b * (VQ_D * VQ_HW) + n0 + wv * 64;

    f16x8 Ah[4][2], Ak[4][2], Ra[4][2];
    #pragma unroll
    for (int tl = 0; tl < 4; ++tl)
        #pragma unroll
        for (int ks = 0; ks < 2; ++ks) {
            f16x8 h8, k8, r8;
            #pragma unroll
            for (int j = 0; j < 8; ++j) {
                const float v = xw[(size_t)(ks * 32 + q * 8 + j) * VQ_HW + tl * 16 + m];
                const _Float16 vh = (_Float16)v;
                h8[j] = vh;
                k8[j] = (_Float16)((float)vh * 2048.0f);     // exact (pow2)
                r8[j] = (_Float16)((v - (float)vh) * SC);
            }
            Ah[tl][ks] = h8; Ak[tl][ks] = k8; Ra[tl][ks] = r8;
        }

    // ---- wait for all 132 prep slices (all 512 blocks co-resident) ----
    if (tid == 0) {
        while (atomicAdd((int*)ws + WS_FLAG, 0) < 132)
            __builtin_amdgcn_s_sleep(2);
    }
    __syncthreads();

    // prologue: stage chunks 0..2, cn_q -> LDS
    STAGE2(0, 0)
    STAGE2(1, 8192)
    STAGE2(2, 16384)
    ((float4*)cnq_lds)[tid] = ((const float4*)(ws + WS_CNQ))[tid];

    int d1[4][4], d2[4][4];
    #pragma unroll
    for (int tl = 0; tl < 4; ++tl)
        #pragma unroll
        for (int r = 0; r < 4; ++r) { d1[tl][r] = 0x7FFFFFFF; d2[tl][r] = 0x7FFFFFFF; }

    const f32x4 zero4 = {0.f, 0.f, 0.f, 0.f};
    const char* lp = (const char*)bbuf + lane * 16;

    __syncthreads();   // one-time full drain: c0-c2 + cnq_lds resident

    // ---- main ring: counted vmcnt, loads stay in flight across barriers ----
    for (int t = 0; t < 29; ++t)
        ITER_T("vmcnt(4)", 1, t)      // steady state: wait oldest of 3 chunks
    ITER_T("vmcnt(4)", 0, 29)         // c29: outstanding c29..c31 -> 4
    ITER_T("vmcnt(2)", 0, 30)         // c30: outstanding c30,c31  -> 2
    ITER_T("vmcnt(0)", 0, 31)         // c31: last

    // ---- top-2 merge across the 16 code-columns (keys carry the code) ----
    #pragma unroll
    for (int off = 1; off < 16; off <<= 1)
        #pragma unroll
        for (int tl = 0; tl < 4; ++tl)
            #pragma unroll
            for (int r = 0; r < 4; ++r) {
                const int od1 = __shfl_xor(d1[tl][r], off, 64);
                const int od2 = __shfl_xor(d2[tl][r], off, 64);
                const int mx  = (d1[tl][r] > od1) ? d1[tl][r] : od1;
                const int mn2 = (d2[tl][r] < od2) ? d2[tl][r] : od2;
                d2[tl][r] = (mx < mn2) ? mx : mn2;
                d1[tl][r] = (d1[tl][r] < od1) ? d1[tl][r] : od1;
            }

    if (m == 0) {
        #pragma unroll
        for (int tl = 0; tl < 4; ++tl)
            #pragma unroll
            for (int r = 0; r < 4; ++r) {
                const int li = wv * 64 + tl * 16 + q * 4 + r;
                sk[li]  = d1[tl][r] & 1023;
                smg[li] = (d2[tl][r] >> 10) - (d1[tl][r] >> 10);   // gap, q-units
            }
    }
    __syncthreads();

    // ---- epilogue: indices, rescan flags, quantized scatter ----
    const int bk = sk[tid];           // 1 thread per position
    idx_out[p0 + tid] = (float)bk;
    if (smg[tid] < EPS_Q) {
        const int slot = atomicAdd((int*)ws + WS_CNT, 1);
        ((int*)ws)[WS_LIST + slot] = p0 + tid;
    }
    const float4* cr = (const float4*)(cb + (size_t)bk * VQ_D);
    float* ob = out + (size_t)b * (VQ_D * VQ_HW) + n0 + tid;
    #pragma unroll
    for (int d4 = 0; d4 < 16; ++d4) {
        const float4 v = cr[d4];
        ob[(size_t)(d4 * 4 + 0) * VQ_HW] = v.x;
        ob[(size_t)(d4 * 4 + 1) * VQ_HW] = v.y;
        ob[(size_t)(d4 * 4 + 2) * VQ_HW] = v.z;
        ob[(size_t)(d4 * 4 + 3) * VQ_HW] = v.w;
    }
}

// ---------- rescan: exact f32 argmin for flagged positions (verified) ----------
__global__ __launch_bounds__(64)
void vq_rescan(const float* __restrict__ x,
               const float* __restrict__ cb,
               const float* __restrict__ ws,
               float* __restrict__ out,
               float* __restrict__ idx_out)
{
    __shared__ float xs[VQ_D];
    const int lane = threadIdx.x;
    const int cnt  = ((const int*)ws)[WS_CNT];
    const int* list = (const int*)ws + WS_LIST;
    const float*  cnb  = ws + WS_CBN;
    const float4* cbT4 = (const float4*)(ws + WS_CBT);

    for (int i = blockIdx.x; i < cnt; i += gridDim.x) {
        const int p = list[i];
        const int b = p >> 12, n = p & (VQ_HW - 1);
        xs[lane] = x[(size_t)b * (VQ_D * VQ_HW) + (size_t)lane * VQ_HW + n];
        __syncthreads();
        float4 xr[16];
        #pragma unroll
        for (int j = 0; j < 16; ++j) xr[j] = ((const float4*)xs)[j];

        float bd = 3.4e38f; int bk = 0;
        #pragma unroll 4
        for (int t = 0; t < 16; ++t) {
            const int code = t * 64 + lane;           // per-lane ascending
            float a0 = 0.f, a1 = 0.f, a2 = 0.f, a3 = 0.f;
            #pragma unroll
            for (int j4 = 0; j4 < 16; ++j4) {
                const float4 c = cbT4[j4 * 1024 + code];   // coalesced
                a0 = fmaf(xr[j4].x, c.x, a0); a1 = fmaf(xr[j4].y, c.y, a1);
                a2 = fmaf(xr[j4].z, c.z, a2); a3 = fmaf(xr[j4].w, c.w, a3);
            }
            const float dist = fmaf(-2.0f, (a0 + a1) + (a2 + a3), cnb[code]);
            if (dist < bd) { bd = dist; bk = code; }
        }
        #pragma unroll
        for (int off = 1; off < 64; off <<= 1) {      // min dist, tie -> min k
            const float od = __shfl_xor(bd, off, 64);
            const int   ok = __shfl_xor(bk, off, 64);
            if (od < bd || (od == bd && ok < bk)) { bd = od; bk = ok; }
        }
        out[(size_t)b * (VQ_D * VQ_HW) + (size_t)lane * VQ_HW + n] = cb[(size_t)bk * VQ_D + lane];
        if (lane == 0) idx_out[p] = (float)bk;
        __syncthreads();
    }
}

extern "C" void kernel_launch(void* const* d_in, const int* in_sizes, int n_in,
                              void* d_out, int out_size, void* d_ws, size_t ws_size,
                              hipStream_t stream) {
    const float* x  = (const float*)d_in[0];
    const float* cb = (const float*)d_in[1];
    float* out = (float*)d_out;
    float* idx = out + (size_t)VQ_NPOS * VQ_D;   // 8,388,608 floats in
    float* ws  = (float*)d_ws;                    // ~1.06 MB used

    hipMemsetAsync((char*)d_ws + (size_t)WS_FLAG * 4, 0, 4, stream);
    vq_main  <<<dim3(512), dim3(256), 0, stream>>>(x, cb, ws, out, idx);
    vq_rescan<<<dim3(256), dim3(64),  0, stream>>>(x, cb, ws, out, idx);
}

// Round 12
// 159.527 us; speedup vs baseline: 1.1235x; 1.1235x over previous
//
#include <hip/hip_runtime.h>

// VectorQuantizer: x (32,64,64,64) f32, codebook (1024,64) f32
// out = concat( quantized (32,64,64,64) f32 , indices (32,64,64) as f32 )
//
// R17 = self-paced wave-private pipelines: NO s_barrier in the main loop.
//  - R16 post-mortem: prep fusion regressed (main 66->82, total 179); revert
//    prep/rescan to R15's separate kernels. Overhead is ~89us stable and
//    partly harness-owned; back to main.
//  - Why 7 structural variants were null: every one kept the per-chunk
//    s_barrier, re-phase-locking the SIMD's waves 32x. Measured ~5400 cyc
//    per SIMD-chunk-pair = MFMA 1864 + VALU ~740 + ~1000 stall, all SERIAL:
//    phase-locked waves burst the same pipe simultaneously, so MFMA, VALU
//    and ds-latency add instead of overlapping.
//  - Fix: each wave owns a 2-slot LDS ring (16KB) and self-stages via
//    global_load_lds; vmcnt is PER-WAVE, so {stage(t+1); vmcnt(8);
//    compute(t)} needs no inter-wave sync. Waves drift anti-phase; one
//    wave's MFMA covers the other's VALU/ds latency; setprio arbitrates
//    (T5's actual regime). Counted vmcnt(8) = newest-8 semantics drains
//    any older stray loads (x A-build) automatically.
//  - Correctness: slots wave-private; chunk t-1 ds_reads are consumed
//    (compiler lgkm waits) before stage t+1 issues in program order; cnq_lds
//    read-only after one prologue __syncthreads; final __syncthreads before
//    the cross-wave epilogue. LDS 70KB -> 2 blocks/CU, grid 512, (256,2).
//  - numerics bit-identical (q-unit int keys, EPS_Q 24, exact-f32 rescan).
//  - tripwires: VGPR <= ~210 (no spill), FETCH ~18.5MB / WRITE ~33.3MB.

typedef _Float16 f16x8 __attribute__((ext_vector_type(8)));
typedef float    f32x4 __attribute__((ext_vector_type(4)));

#define VQ_D    64
#define VQ_HW   4096
#define VQ_NPOS 131072
#define SC      2048.0f
#define EPS_Q   24         // flag margin in q-units (24/2048 = 1.17e-2)
// ws float offsets (stream = 32 chunks * 8192B = 256KB = 65536 floats)
#define WS_CBN  65536      // f32 cn[1024] raw (rescan)
#define WS_CNQ  66560      // f32 cn_q[1024] = 2048*cn (main C-init)
#define WS_CBT  67584      // float4 cbT4[16384] (256 KB)
#define WS_CNT  133120     // int rescan counter
#define WS_LIST 133124     // int list[131072]

// ---------- prep (identical to R13/R14/R15, verified) ----------
__global__ __launch_bounds__(256)
void vq_prep(const float* __restrict__ cb, float* __restrict__ ws)
{
    const int tid = threadIdx.x;
    const int blk = blockIdx.x;
    if (blk < 64) {
        const int it   = blk * 256 + tid;            // [0, 16384)
        const int ct   = it >> 8;
        const int s    = (it >> 6) & 3;
        const int lane = it & 63;
        const int ks   = s & 1, isR = s >> 1;
        const int n    = ct * 16 + (lane & 15);      // code (B column)
        const int k0   = ks * 32 + (lane >> 4) * 8;  // dim  (B row)
        const float* src = cb + n * 64 + k0;
        f16x8 o;
        #pragma unroll
        for (int j = 0; j < 8; ++j) {
            const float b = src[j];
            const _Float16 bh = (_Float16)b;
            o[j] = isR ? (_Float16)((b - (float)bh) * (-2.0f * SC))
                       : (_Float16)(-2.0f * (float)bh);
        }
        ((f16x8*)ws)[it] = o;
    } else if (blk < 128) {
        const int it = (blk - 64) * 256 + tid;       // [0, 16384)
        const int k = it >> 4, j4 = it & 15;
        ((float4*)(ws + WS_CBT))[j4 * 1024 + k] = ((const float4*)cb)[it];
    } else {
        const int k = (blk - 128) * 256 + tid;       // [0, 1024)
        const float4* row = (const float4*)(cb + k * 64);
        float a0 = 0.f, a1 = 0.f, a2 = 0.f, a3 = 0.f;
        #pragma unroll
        for (int j = 0; j < 16; ++j) {
            const float4 c = row[j];
            a0 = fmaf(c.x, c.x, a0); a1 = fmaf(c.y, c.y, a1);
            a2 = fmaf(c.z, c.z, a2); a3 = fmaf(c.w, c.w, a3);
        }
        const float cn = (a0 + a1) + (a2 + a3);
        ws[WS_CBN + k] = cn;                         // raw (rescan)
        ws[WS_CNQ + k] = cn * 2048.0f;               // q-units (main)
        if (k == 0) ((int*)ws)[WS_CNT] = 0;
    }
}

// ---------- main ----------
#define GLOAD_LDS(GP, LP)                                                     \
    __builtin_amdgcn_global_load_lds(                                         \
        (const __attribute__((address_space(1))) unsigned int*)(GP),          \
        (__attribute__((address_space(3))) unsigned int*)(LP), 16, 0, 0)

// wave-private stage: full 8KB chunk CK -> own ring slot SLOT (8 gloads).
// LDS dst is wave-uniform base (HW adds lane*16); src is per-lane.
#define STAGEW(CK, SLOT)                                                      \
    {                                                                         \
        const char* gs_ = (const char*)ws + (size_t)(CK) * 8192 + lane * 16;  \
        char* ld_ = myring + (SLOT) * 8192;                                   \
        GLOAD_LDS(gs_,        ld_);        GLOAD_LDS(gs_ + 1024, ld_ + 1024); \
        GLOAD_LDS(gs_ + 2048, ld_ + 2048); GLOAD_LDS(gs_ + 3072, ld_ + 3072); \
        GLOAD_LDS(gs_ + 4096, ld_ + 4096); GLOAD_LDS(gs_ + 5120, ld_ + 5120); \
        GLOAD_LDS(gs_ + 6144, ld_ + 6144); GLOAD_LDS(gs_ + 7168, ld_ + 7168); \
    }

// one 16-code tile, 4 M-tiles: 8 independent depth-3 chains (pa/pb per tile),
// 24 MFMAs; then 1 add + int-key update per output (16 outputs).
#define CT_BODY(BOFF, CI, CTG)                                                \
    {                                                                         \
        const f16x8 B0 = *(const f16x8*)(lp + (BOFF) + (CI) * 4096);          \
        const f16x8 B1 = *(const f16x8*)(lp + (BOFF) + (CI) * 4096 + 1024);   \
        const f16x8 R0 = *(const f16x8*)(lp + (BOFF) + (CI) * 4096 + 2048);   \
        const f16x8 R1 = *(const f16x8*)(lp + (BOFF) + (CI) * 4096 + 3072);   \
        const float cvq = cnq_lds[(CTG) * 16 + m];                            \
        const f32x4 Ci = {cvq, cvq, cvq, cvq};                                \
        f32x4 pa[4], pb[4];                                                   \
        __builtin_amdgcn_s_setprio(1);                                        \
        _Pragma("unroll")                                                     \
        for (int tl = 0; tl < 4; ++tl) {                                      \
            pa[tl] = __builtin_amdgcn_mfma_f32_16x16x32_f16(Ak[tl][0], B0, Ci,    0,0,0); \
            pb[tl] = __builtin_amdgcn_mfma_f32_16x16x32_f16(Ak[tl][1], B1, zero4, 0,0,0); \
        }                                                                     \
        _Pragma("unroll")                                                     \
        for (int tl = 0; tl < 4; ++tl) {                                      \
            pa[tl] = __builtin_amdgcn_mfma_f32_16x16x32_f16(Ah[tl][0], R0, pa[tl], 0,0,0); \
            pb[tl] = __builtin_amdgcn_mfma_f32_16x16x32_f16(Ah[tl][1], R1, pb[tl], 0,0,0); \
        }                                                                     \
        _Pragma("unroll")                                                     \
        for (int tl = 0; tl < 4; ++tl) {                                      \
            pa[tl] = __builtin_amdgcn_mfma_f32_16x16x32_f16(Ra[tl][0], B0, pa[tl], 0,0,0); \
            pb[tl] = __builtin_amdgcn_mfma_f32_16x16x32_f16(Ra[tl][1], B1, pb[tl], 0,0,0); \
        }                                                                     \
        __builtin_amdgcn_s_setprio(0);                                        \
        const int cbase_ = (CTG) * 16 + m;                                    \
        _Pragma("unroll")                                                     \
        for (int tl = 0; tl < 4; ++tl)                                        \
            _Pragma("unroll")                                                 \
            for (int r = 0; r < 4; ++r) {                                     \
                const float q_ = pa[tl][r] + pb[tl][r];                       \
                const int k_ = ((int)q_ << 10) | cbase_;                      \
                int md_;                                                      \
                asm("v_med3_i32 %0, %1, %2, %3"                               \
                    : "=v"(md_) : "v"(k_), "v"(d1[tl][r]), "v"(d2[tl][r]));   \
                d2[tl][r] = md_;                                              \
                d1[tl][r] = (k_ < d1[tl][r]) ? k_ : d1[tl][r];                \
            }                                                                 \
    }

__global__ __launch_bounds__(256, 2)
void vq_main(const float* __restrict__ x,
             const float* __restrict__ cb,
             float* __restrict__ ws,
             float* __restrict__ out,
             float* __restrict__ idx_out)
{
    __shared__ f16x8 bbuf[4 * 1024];  // 4 waves x private 2-slot ring (16KB)
    __shared__ float cnq_lds[1024];   // 2048*||e||^2 (read-only after barrier)
    __shared__ int   sk[256];
    __shared__ int   smg[256];

    const int tid  = threadIdx.x;
    const int lane = tid & 63;
    const int wv   = tid >> 6;        // 4 waves, 64 positions each
    const int m    = lane & 15;
    const int q    = lane >> 4;

    const int p0 = blockIdx.x * 256;  // block: 256 consecutive positions
    const int b  = p0 >> 12;
    const int n0 = p0 & (VQ_HW - 1);
    const float* xw = x + (size_t)b * (VQ_D * VQ_HW) + n0 + wv * 64;

    char* myring = (char*)bbuf + wv * 16384;   // wave-private 2x8KB ring

    // ---- A fragments from x (vmem loads fully consumed here) ----
    f16x8 Ah[4][2], Ak[4][2], Ra[4][2];
    #pragma unroll
    for (int tl = 0; tl < 4; ++tl)
        #pragma unroll
        for (int ks = 0; ks < 2; ++ks) {
            f16x8 h8, k8, r8;
            #pragma unroll
            for (int j = 0; j < 8; ++j) {
                const float v = xw[(size_t)(ks * 32 + q * 8 + j) * VQ_HW + tl * 16 + m];
                const _Float16 vh = (_Float16)v;
                h8[j] = vh;
                k8[j] = (_Float16)((float)vh * 2048.0f);     // exact (pow2)
                r8[j] = (_Float16)((v - (float)vh) * SC);
            }
            Ah[tl][ks] = h8; Ak[tl][ks] = k8; Ra[tl][ks] = r8;
        }

    // cn_q -> LDS (once), then the ONLY pre-loop barrier
    ((float4*)cnq_lds)[tid] = ((const float4*)(ws + WS_CNQ))[tid];
    __syncthreads();

    int d1[4][4], d2[4][4];
    #pragma unroll
    for (int tl = 0; tl < 4; ++tl)
        #pragma unroll
        for (int r = 0; r < 4; ++r) { d1[tl][r] = 0x7FFFFFFF; d2[tl][r] = 0x7FFFFFFF; }

    const f32x4 zero4 = {0.f, 0.f, 0.f, 0.f};
    const char* lp = (const char*)bbuf + wv * 16384 + lane * 16;

    // ---- self-paced ring: per-wave counted vmcnt, NO barriers ----
    STAGEW(0, 0)                      // prologue: chunk 0 -> slot 0
    for (int t = 0; t < 31; ++t) {
        STAGEW(t + 1, (t + 1) & 1)    // issue next chunk into other slot
        asm volatile("s_waitcnt vmcnt(8)" ::: "memory");  // own chunk-t done
        const int base_ = (t & 1) * 8192;
        CT_BODY(base_, 0, t * 2)
        CT_BODY(base_, 1, t * 2 + 1)
    }
    asm volatile("s_waitcnt vmcnt(0)" ::: "memory");      // last chunk
    CT_BODY(8192, 0, 62)
    CT_BODY(8192, 1, 63)

    // ---- top-2 merge across the 16 code-columns (keys carry the code) ----
    #pragma unroll
    for (int off = 1; off < 16; off <<= 1)
        #pragma unroll
        for (int tl = 0; tl < 4; ++tl)
            #pragma unroll
            for (int r = 0; r < 4; ++r) {
                const int od1 = __shfl_xor(d1[tl][r], off, 64);
                const int od2 = __shfl_xor(d2[tl][r], off, 64);
                const int mx  = (d1[tl][r] > od1) ? d1[tl][r] : od1;
                const int mn2 = (d2[tl][r] < od2) ? d2[tl][r] : od2;
                d2[tl][r] = (mx < mn2) ? mx : mn2;
                d1[tl][r] = (d1[tl][r] < od1) ? d1[tl][r] : od1;
            }

    if (m == 0) {
        #pragma unroll
        for (int tl = 0; tl < 4; ++tl)
            #pragma unroll
            for (int r = 0; r < 4; ++r) {
                const int li = wv * 64 + tl * 16 + q * 4 + r;
                sk[li]  = d1[tl][r] & 1023;
                smg[li] = (d2[tl][r] >> 10) - (d1[tl][r] >> 10);   // gap, q-units
            }
    }
    __syncthreads();

    // ---- epilogue: indices, rescan flags, quantized scatter ----
    const int bk = sk[tid];           // 1 thread per position
    idx_out[p0 + tid] = (float)bk;
    if (smg[tid] < EPS_Q) {
        const int slot = atomicAdd((int*)ws + WS_CNT, 1);
        ((int*)ws)[WS_LIST + slot] = p0 + tid;
    }
    const float4* cr = (const float4*)(cb + (size_t)bk * VQ_D);
    float* ob = out + (size_t)b * (VQ_D * VQ_HW) + n0 + tid;
    #pragma unroll
    for (int d4 = 0; d4 < 16; ++d4) {
        const float4 v = cr[d4];
        ob[(size_t)(d4 * 4 + 0) * VQ_HW] = v.x;
        ob[(size_t)(d4 * 4 + 1) * VQ_HW] = v.y;
        ob[(size_t)(d4 * 4 + 2) * VQ_HW] = v.z;
        ob[(size_t)(d4 * 4 + 3) * VQ_HW] = v.w;
    }
}

// ---------- rescan: exact f32 argmin for flagged positions (verified) ----------
__global__ __launch_bounds__(64)
void vq_rescan(const float* __restrict__ x,
               const float* __restrict__ cb,
               const float* __restrict__ ws,
               float* __restrict__ out,
               float* __restrict__ idx_out)
{
    __shared__ float xs[VQ_D];
    const int lane = threadIdx.x;
    const int cnt  = ((const int*)ws)[WS_CNT];
    const int* list = (const int*)ws + WS_LIST;
    const float*  cnb  = ws + WS_CBN;
    const float4* cbT4 = (const float4*)(ws + WS_CBT);

    for (int i = blockIdx.x; i < cnt; i += gridDim.x) {
        const int p = list[i];
        const int b = p >> 12, n = p & (VQ_HW - 1);
        xs[lane] = x[(size_t)b * (VQ_D * VQ_HW) + (size_t)lane * VQ_HW + n];
        __syncthreads();
        float4 xr[16];
        #pragma unroll
        for (int j = 0; j < 16; ++j) xr[j] = ((const float4*)xs)[j];

        float bd = 3.4e38f; int bk = 0;
        #pragma unroll 4
        for (int t = 0; t < 16; ++t) {
            const int code = t * 64 + lane;           // per-lane ascending
            float a0 = 0.f, a1 = 0.f, a2 = 0.f, a3 = 0.f;
            #pragma unroll
            for (int j4 = 0; j4 < 16; ++j4) {
                const float4 c = cbT4[j4 * 1024 + code];   // coalesced
                a0 = fmaf(xr[j4].x, c.x, a0); a1 = fmaf(xr[j4].y, c.y, a1);
                a2 = fmaf(xr[j4].z, c.z, a2); a3 = fmaf(xr[j4].w, c.w, a3);
            }
            const float dist = fmaf(-2.0f, (a0 + a1) + (a2 + a3), cnb[code]);
            if (dist < bd) { bd = dist; bk = code; }
        }
        #pragma unroll
        for (int off = 1; off < 64; off <<= 1) {      // min dist, tie -> min k
            const float od = __shfl_xor(bd, off, 64);
            const int   ok = __shfl_xor(bk, off, 64);
            if (od < bd || (od == bd && ok < bk)) { bd = od; bk = ok; }
        }
        out[(size_t)b * (VQ_D * VQ_HW) + (size_t)lane * VQ_HW + n] = cb[(size_t)bk * VQ_D + lane];
        if (lane == 0) idx_out[p] = (float)bk;
        __syncthreads();
    }
}

extern "C" void kernel_launch(void* const* d_in, const int* in_sizes, int n_in,
                              void* d_out, int out_size, void* d_ws, size_t ws_size,
                              hipStream_t stream) {
    const float* x  = (const float*)d_in[0];
    const float* cb = (const float*)d_in[1];
    float* out = (float*)d_out;
    float* idx = out + (size_t)VQ_NPOS * VQ_D;   // 8,388,608 floats in
    float* ws  = (float*)d_ws;                    // ~1.06 MB used

    vq_prep  <<<dim3(132),  dim3(256), 0, stream>>>(cb, ws);
    vq_main  <<<dim3(512),  dim3(256), 0, stream>>>(x, cb, ws, out, idx);
    vq_rescan<<<dim3(1024), dim3(64),  0, stream>>>(x, cb, ws, out, idx);
}